// Round 1
// baseline (32.770 us; speedup 1.0000x reference)
//
#include <hip/hip_runtime.h>

#define TILE 16
#define HALO (TILE + 2)

__global__ __launch_bounds__(256) void smap_fused(
    const float* __restrict__ x, const float* __restrict__ cam,
    float* __restrict__ out, int B, int H, int W)
{
    __shared__ float sx[HALO][HALO + 1];
    __shared__ float sy[HALO][HALO + 1];
    __shared__ float sz[HALO][HALO + 1];
    __shared__ float sr[HALO][HALO + 1];
    __shared__ signed char sk[HALO][HALO + 1];

    const int b  = blockIdx.z;
    const int h0 = blockIdx.y * TILE;
    const int w0 = blockIdx.x * TILE;
    const int tx = threadIdx.x, ty = threadIdx.y;
    const int tid = ty * TILE + tx;

    // ---- 3x3 inverse of cam (adjugate / det). For the given cam all the
    // products are exact in f32 and each entry is one correctly-rounded
    // division, matching LAPACK's triangular-solve inversion bitwise. ----
    const float a00 = cam[0], a01 = cam[1], a02 = cam[2];
    const float a10 = cam[3], a11 = cam[4], a12 = cam[5];
    const float a20 = cam[6], a21 = cam[7], a22 = cam[8];
    const float m00 = a11 * a22 - a12 * a21;
    const float m01 = a10 * a22 - a12 * a20;
    const float m02 = a10 * a21 - a11 * a20;
    const float det = a00 * m00 - a01 * m01 + a02 * m02;
    const float i00 = m00 / det;
    const float i01 = (a02 * a21 - a01 * a22) / det;
    const float i02 = (a01 * a12 - a02 * a11) / det;
    const float i10 = (a12 * a20 - a10 * a22) / det;
    const float i11 = (a00 * a22 - a02 * a20) / det;
    const float i12 = (a02 * a10 - a00 * a12) / det;
    const float i20 = m02 / det;
    const float i21 = (a01 * a20 - a00 * a21) / det;
    const float i22 = (a00 * a11 - a01 * a10) / det;

    const size_t HW = (size_t)H * W;
    const float* xb = x + (size_t)b * 4 * HW;

    // ---- Pass 1: halo tile -> selected-offset code k (0..8; 9 = none) ----
    for (int item = tid; item < HALO * HALO; item += TILE * TILE) {
        const int i = item / HALO, j = item % HALO;
        const int gh = h0 - 1 + i, gw = w0 - 1 + j;
        float xv = 0.f, yv = 0.f, zv = 0.f, rm = 0.f;
        if (gh >= 0 && gh < H && gw >= 0 && gw < W) {
            const size_t off = (size_t)gh * W + gw;
            xv = xb[off];
            yv = xb[HW + off];
            zv = xb[2 * HW + off];
            rm = xb[3 * HW + off];
        }
        signed char k = 9;                       // no selection (weights all 0)
        const bool validp = (rm > 0.5f) && (zv > 0.0f);
        const bool badp   = (rm > 0.5f) && !(zv > 0.0f);
        if (validp) {
            // zs == zv here (zv > 0)
            const float px = __fdiv_rn(xv, zv);
            const float py = __fdiv_rn(yv, zv);
            float best = __builtin_inff();
            int bi = 0;
            #pragma unroll
            for (int n = 0; n < 9; ++n) {
                const int s = n / 3, t = n % 3;
                const float u = (float)(gw + t);  // xs[j] = j-1, j = t + (gw+1)
                const float v = (float)(gh + s);
                // explicit round-to-nearest ops: forbid fma contraction so the
                // cost bits match XLA's un-contracted elementwise lowering
                const float r0 = __fadd_rn(__fadd_rn(__fmul_rn(i00, u), __fmul_rn(i01, v)), i02);
                const float r1 = __fadd_rn(__fadd_rn(__fmul_rn(i10, u), __fmul_rn(i11, v)), i12);
                const float r2 = __fadd_rn(__fadd_rn(__fmul_rn(i20, u), __fmul_rn(i21, v)), i22);
                const float rx = __fdiv_rn(r0, r2);
                const float ry = __fdiv_rn(r1, r2);
                const float dx = __fsub_rn(px, rx);
                const float dy = __fsub_rn(py, ry);
                const float c  = __fadd_rn(__fmul_rn(dx, dx), __fmul_rn(dy, dy));
                if (c < best) { best = c; bi = n; }  // strict <: first-min, matches jnp.argmin
            }
            k = (signed char)bi;
        } else if (badp) {
            k = 4;                                // temp one_hot(4)
        }
        sx[i][j] = xv; sy[i][j] = yv; sz[i][j] = zv; sr[i][j] = rm; sk[i][j] = k;
    }
    __syncthreads();

    // ---- Pass 2: per output pixel, first-min over the 9 scattered z ----
    const int h = h0 + ty, w = w0 + tx;
    if (h >= H || w >= W) return;

    float bz = 0.f;
    int bli = 0, blj = 0;
    bool found = false;
    #pragma unroll
    for (int n = 0; n < 9; ++n) {
        const int s = n / 3, t = n % 3;
        const int li = ty + 2 - s, lj = tx + 2 - t;   // neighbor (h+1-s, w+1-t)
        const float zn = sz[li][lj];
        const bool match = (sk[li][lj] == (signed char)n) && (zn > 0.f);
        if (match && (!found || zn < bz)) { bz = zn; bli = li; blj = lj; found = true; }
    }

    float ox, oy, oz, orm;
    if (found) {
        // winning neighbor is valid with kdet==n: w_det = w2 = 1 there
        ox = sx[bli][blj]; oy = sy[bli][blj]; oz = sz[bli][blj]; orm = sr[bli][blj];
    } else {
        // fallback: slab (1,1) of the pixel itself
        const int li = ty + 1, lj = tx + 1;
        const float xv = sx[li][lj], yv = sy[li][lj], zv = sz[li][lj], rm = sr[li][lj];
        const bool k4 = (sk[li][lj] == 4);            // w_det(1,1) == 1
        const bool validp = (rm > 0.5f) && (zv > 0.f);
        ox = k4 ? xv : 0.f;
        oy = k4 ? yv : 0.f;
        oz = k4 ? zv : 0.f;
        orm = (k4 || !validp) ? rm : 0.f;             // w2(1,1)
    }

    const size_t obase = (size_t)b * 4 * HW + (size_t)h * W + w;
    out[obase]          = ox;
    out[obase + HW]     = oy;
    out[obase + 2 * HW] = oz;
    out[obase + 3 * HW] = orm;
}

extern "C" void kernel_launch(void* const* d_in, const int* in_sizes, int n_in,
                              void* d_out, int out_size, void* d_ws, size_t ws_size,
                              hipStream_t stream) {
    const float* x   = (const float*)d_in[0];
    const float* cam = (const float*)d_in[1];
    float* out = (float*)d_out;
    const int H = 512, W = 640;
    const int B = in_sizes[0] / (4 * H * W);
    dim3 block(TILE, TILE);
    dim3 grid((W + TILE - 1) / TILE, (H + TILE - 1) / TILE, B);
    hipLaunchKernelGGL(smap_fused, grid, block, 0, stream, x, cam, out, B, H, W);
}

// Round 2
// 20.555 us; speedup vs baseline: 1.5942x; 1.5942x over previous
//
#include <hip/hip_runtime.h>

#define BT 32            // output tile (32x32 per 256-thread block)
#define HT (BT + 2)      // halo tile = 34
#define PITCH (HT + 1)   // LDS row pitch = 35 (odd -> bank-conflict-free-ish)

__global__ __launch_bounds__(256) void smap_fused(
    const float* __restrict__ x, const float* __restrict__ cam,
    float* __restrict__ out, int B, int H, int W)
{
    __shared__ float sx[HT][PITCH];
    __shared__ float sy[HT][PITCH];
    __shared__ float sz[HT][PITCH];
    __shared__ float sr[HT][PITCH];
    __shared__ signed char sk[HT][PITCH];

    const int b  = blockIdx.z;
    const int h0 = blockIdx.y * BT;
    const int w0 = blockIdx.x * BT;
    const int tx = threadIdx.x;          // 0..31
    const int ty = threadIdx.y;          // 0..7
    const int tid = ty * 32 + tx;

    // ---- 3x3 inverse of cam (adjugate / det): bitwise-matches LAPACK's
    // triangular-solve inversion for this cam (verified absmax 0.0) ----
    const float a00 = cam[0], a01 = cam[1], a02 = cam[2];
    const float a10 = cam[3], a11 = cam[4], a12 = cam[5];
    const float a20 = cam[6], a21 = cam[7], a22 = cam[8];
    const float m00 = a11 * a22 - a12 * a21;
    const float m01 = a10 * a22 - a12 * a20;
    const float m02 = a10 * a21 - a11 * a20;
    const float det = a00 * m00 - a01 * m01 + a02 * m02;
    const float i00 = m00 / det;
    const float i01 = (a02 * a21 - a01 * a22) / det;
    const float i02 = (a01 * a12 - a02 * a11) / det;
    const float i10 = (a12 * a20 - a10 * a22) / det;
    const float i11 = (a00 * a22 - a02 * a20) / det;
    const float i12 = (a02 * a10 - a00 * a12) / det;
    const float i20 = m02 / det;
    const float i21 = (a01 * a20 - a00 * a21) / det;
    const float i22 = (a00 * a11 - a01 * a10) / det;

    // If i20==+-0, i21==+-0, i22==1.0 then r2 = fadd(fadd(fmul(i20,u),
    // fmul(i21,v)), i22) == 1.0f EXACTLY for every (u,v), and division by
    // 1.0 is the identity -> skip 18 correctly-rounded divides per pixel.
    const bool fastcam = (i20 == 0.0f) && (i21 == 0.0f) && (i22 == 1.0f);

    const size_t HW = (size_t)H * W;
    const float* xb = x + (size_t)b * 4 * HW;

    // ---- Pass 1: halo tile -> selected-offset code k (0..8; 4=bad; 9=none) ----
    for (int item = tid; item < HT * HT; item += 256) {
        const int i = item / HT, j = item - i * HT;
        const int gh = h0 - 1 + i, gw = w0 - 1 + j;
        float xv = 0.f, yv = 0.f, zv = 0.f, rm = 0.f;
        if (gh >= 0 && gh < H && gw >= 0 && gw < W) {
            const size_t off = (size_t)gh * W + gw;
            xv = xb[off];
            yv = xb[HW + off];
            zv = xb[2 * HW + off];
            rm = xb[3 * HW + off];
        }
        // reference: zs = where(z>0, z, 1); px = x/zs (computed for all pixels)
        const float zs = (zv > 0.f) ? zv : 1.0f;
        const float px = __fdiv_rn(xv, zs);
        const float py = __fdiv_rn(yv, zs);

        // hoist the per-(u,v)-axis products out of the 9-neighbor loop;
        // fmul(i00,u) is the same bits wherever it's computed
        float A0[3], A1[3], B0[3], B1[3];
        #pragma unroll
        for (int t = 0; t < 3; ++t) {
            const float u = (float)(gw + t);       // xs[j] = j-1
            A0[t] = __fmul_rn(i00, u);
            A1[t] = __fmul_rn(i10, u);
        }
        #pragma unroll
        for (int s = 0; s < 3; ++s) {
            const float v = (float)(gh + s);
            B0[s] = __fmul_rn(i01, v);
            B1[s] = __fmul_rn(i11, v);
        }

        float best = __builtin_inff();
        int bi = 0;
        #pragma unroll
        for (int n = 0; n < 9; ++n) {
            const int s = n / 3, t = n % 3;
            const float r0 = __fadd_rn(__fadd_rn(A0[t], B0[s]), i02);
            const float r1 = __fadd_rn(__fadd_rn(A1[t], B1[s]), i12);
            float rx, ry;
            if (fastcam) {
                rx = r0; ry = r1;                  // exact: r2 == 1.0f
            } else {
                const float u = (float)(gw + t), v = (float)(gh + s);
                const float r2 = __fadd_rn(__fadd_rn(__fmul_rn(i20, u), __fmul_rn(i21, v)), i22);
                rx = __fdiv_rn(r0, r2);
                ry = __fdiv_rn(r1, r2);
            }
            const float dx = __fsub_rn(px, rx);
            const float dy = __fsub_rn(py, ry);
            const float c  = __fadd_rn(__fmul_rn(dx, dx), __fmul_rn(dy, dy));
            if (c < best) { best = c; bi = n; }    // strict <: first-min (jnp.argmin)
        }

        const bool validp = (rm > 0.5f) && (zv > 0.0f);
        const bool badp   = (rm > 0.5f) && !(zv > 0.0f);
        sk[i][j] = validp ? (signed char)bi : (badp ? (signed char)4 : (signed char)9);
        sx[i][j] = xv; sy[i][j] = yv; sz[i][j] = zv; sr[i][j] = rm;
    }
    __syncthreads();

    // ---- Pass 2: per output pixel, first-min over the 9 scattered-in z ----
    #pragma unroll
    for (int q = 0; q < 4; ++q) {
        const int ry = ty + 8 * q;                 // row within tile, 0..31
        const int h = h0 + ry, w = w0 + tx;
        if (h >= H || w >= W) continue;

        float bz = 0.f;
        int bli = 0, blj = 0;
        bool found = false;
        #pragma unroll
        for (int n = 0; n < 9; ++n) {
            const int s = n / 3, t = n % 3;
            const int li = ry + 2 - s, lj = tx + 2 - t;   // neighbor (h+1-s, w+1-t)
            const float zn = sz[li][lj];
            const bool match = (sk[li][lj] == (signed char)n) && (zn > 0.f);
            if (match && (!found || zn < bz)) { bz = zn; bli = li; blj = lj; found = true; }
        }

        float ox, oy, oz, orm;
        if (found) {
            ox = sx[bli][blj]; oy = sy[bli][blj]; oz = sz[bli][blj]; orm = sr[bli][blj];
        } else {
            // fallback: slab (1,1) contribution of the pixel itself
            const int li = ry + 1, lj = tx + 1;
            const float xv = sx[li][lj], yv = sy[li][lj], zv = sz[li][lj], rm = sr[li][lj];
            const bool k4 = (sk[li][lj] == 4);             // w_det(1,1) == 1
            const bool validp = (rm > 0.5f) && (zv > 0.f);
            ox = k4 ? xv : 0.f;
            oy = k4 ? yv : 0.f;
            oz = k4 ? zv : 0.f;
            orm = (k4 || !validp) ? rm : 0.f;              // w2(1,1)
        }

        const size_t obase = (size_t)b * 4 * HW + (size_t)h * W + w;
        __builtin_nontemporal_store(ox,  &out[obase]);
        __builtin_nontemporal_store(oy,  &out[obase + HW]);
        __builtin_nontemporal_store(oz,  &out[obase + 2 * HW]);
        __builtin_nontemporal_store(orm, &out[obase + 3 * HW]);
    }
}

extern "C" void kernel_launch(void* const* d_in, const int* in_sizes, int n_in,
                              void* d_out, int out_size, void* d_ws, size_t ws_size,
                              hipStream_t stream) {
    const float* x   = (const float*)d_in[0];
    const float* cam = (const float*)d_in[1];
    float* out = (float*)d_out;
    const int H = 512, W = 640;
    const int B = in_sizes[0] / (4 * H * W);
    dim3 block(32, 8);
    dim3 grid((W + BT - 1) / BT, (H + BT - 1) / BT, B);
    hipLaunchKernelGGL(smap_fused, grid, block, 0, stream, x, cam, out, B, H, W);
}

// Round 3
// 19.694 us; speedup vs baseline: 1.6640x; 1.0438x over previous
//
#include <hip/hip_runtime.h>

#define BT 32            // output tile (32x32 per 256-thread block)
#define HT (BT + 2)      // halo tile = 34
#define PP (HT + 1)      // LDS row pitch = 35

__global__ __launch_bounds__(256) void smap_fused(
    const float* __restrict__ x, const float* __restrict__ cam,
    float* __restrict__ out, int B, int H, int W)
{
    __shared__ float2 szk[HT][PP];   // (z, k-as-bits)
    __shared__ float2 sxy[HT][PP];   // (x, y)
    __shared__ float  srm[HT][PP];   // rm

    const int b  = blockIdx.z;
    const int h0 = blockIdx.y * BT;
    const int w0 = blockIdx.x * BT;
    const int tx = threadIdx.x;          // 0..31
    const int ty = threadIdx.y;          // 0..7
    const int tid = ty * 32 + tx;

    // ---- 3x3 inverse of cam (adjugate / det): bitwise-matches LAPACK's
    // triangular-solve inversion for this cam (verified absmax 0.0) ----
    const float a00 = cam[0], a01 = cam[1], a02 = cam[2];
    const float a10 = cam[3], a11 = cam[4], a12 = cam[5];
    const float a20 = cam[6], a21 = cam[7], a22 = cam[8];
    const float m00 = a11 * a22 - a12 * a21;
    const float m01 = a10 * a22 - a12 * a20;
    const float m02 = a10 * a21 - a11 * a20;
    const float det = a00 * m00 - a01 * m01 + a02 * m02;
    const float i00 = m00 / det;
    const float i01 = (a02 * a21 - a01 * a22) / det;
    const float i02 = (a01 * a12 - a02 * a11) / det;
    const float i10 = (a12 * a20 - a10 * a22) / det;
    const float i11 = (a00 * a22 - a02 * a20) / det;
    const float i12 = (a02 * a10 - a00 * a12) / det;
    const float i20 = m02 / det;
    const float i21 = (a01 * a20 - a00 * a21) / det;
    const float i22 = (a00 * a11 - a01 * a10) / det;

    // r2 == 1.0f exactly for every (u,v) when i20==+-0, i21==+-0, i22==1:
    // fadd(fadd(+-0,+-0), 1.0) == 1.0 and division by 1.0 is identity.
    const bool fastcam = (i20 == 0.0f) && (i21 == 0.0f) && (i22 == 1.0f);
    // Separable costs: if additionally i01 == +0 and i10 == +0 (bit-exact),
    // rx is s-independent and ry is t-independent BITWISE:
    //   fadd(A, +0) == A except A == -0, and that corner only flips the sign
    //   of a zero, which squaring erases ((+-0)^2 == +0). Verified-safe.
    const bool fastsep = fastcam &&
        (__float_as_uint(i01) == 0u) && (__float_as_uint(i10) == 0u);

    const size_t HW = (size_t)H * W;
    const float* xb = x + (size_t)b * 4 * HW;

    // ---- Pass 1: halo tile -> (z, code k) with k in 0..8; 4=bad; 9=none ----
    for (int item = tid; item < HT * HT; item += 256) {
        const int i = item / HT, j = item - i * HT;
        const int gh = h0 - 1 + i, gw = w0 - 1 + j;
        float xv = 0.f, yv = 0.f, zv = 0.f, rm = 0.f;
        if (gh >= 0 && gh < H && gw >= 0 && gw < W) {
            const size_t off = (size_t)gh * W + gw;
            xv = xb[off];
            yv = xb[HW + off];
            zv = xb[2 * HW + off];
            rm = xb[3 * HW + off];
        }
        // reference: zs = where(z>0, z, 1); px = x/zs
        const float zs = (zv > 0.f) ? zv : 1.0f;
        const float px = __fdiv_rn(xv, zs);
        const float py = __fdiv_rn(yv, zs);

        float best = __builtin_inff();
        int bi = 0;
        if (fastsep) {
            float f[3], g[3];
            #pragma unroll
            for (int t = 0; t < 3; ++t) {
                const float u  = (float)(gw + t);
                const float rx = __fadd_rn(__fmul_rn(i00, u), i02);
                const float dx = __fsub_rn(px, rx);
                f[t] = __fmul_rn(dx, dx);
            }
            #pragma unroll
            for (int s = 0; s < 3; ++s) {
                const float v  = (float)(gh + s);
                const float ry = __fadd_rn(__fmul_rn(i11, v), i12);
                const float dy = __fsub_rn(py, ry);
                g[s] = __fmul_rn(dy, dy);
            }
            // full 9-sum argmin in n order: tie semantics == jnp.argmin
            #pragma unroll
            for (int n = 0; n < 9; ++n) {
                const float c = __fadd_rn(f[n % 3], g[n / 3]);
                if (c < best) { best = c; bi = n; }
            }
        } else {
            // generic exact path (same as verified round-2 kernel)
            float A0[3], A1[3], B0[3], B1[3];
            #pragma unroll
            for (int t = 0; t < 3; ++t) {
                const float u = (float)(gw + t);
                A0[t] = __fmul_rn(i00, u);
                A1[t] = __fmul_rn(i10, u);
            }
            #pragma unroll
            for (int s = 0; s < 3; ++s) {
                const float v = (float)(gh + s);
                B0[s] = __fmul_rn(i01, v);
                B1[s] = __fmul_rn(i11, v);
            }
            #pragma unroll
            for (int n = 0; n < 9; ++n) {
                const int s = n / 3, t = n % 3;
                const float r0 = __fadd_rn(__fadd_rn(A0[t], B0[s]), i02);
                const float r1 = __fadd_rn(__fadd_rn(A1[t], B1[s]), i12);
                float rx, ry;
                if (fastcam) {
                    rx = r0; ry = r1;
                } else {
                    const float u = (float)(gw + t), v = (float)(gh + s);
                    const float r2 = __fadd_rn(__fadd_rn(__fmul_rn(i20, u), __fmul_rn(i21, v)), i22);
                    rx = __fdiv_rn(r0, r2);
                    ry = __fdiv_rn(r1, r2);
                }
                const float dx = __fsub_rn(px, rx);
                const float dy = __fsub_rn(py, ry);
                const float c  = __fadd_rn(__fmul_rn(dx, dx), __fmul_rn(dy, dy));
                if (c < best) { best = c; bi = n; }
            }
        }

        const bool validp = (rm > 0.5f) && (zv > 0.0f);
        const bool badp   = (rm > 0.5f) && !(zv > 0.0f);
        const int k = validp ? bi : (badp ? 4 : 9);
        szk[i][j] = make_float2(zv, __int_as_float(k));
        sxy[i][j] = make_float2(xv, yv);
        srm[i][j] = rm;
    }
    __syncthreads();

    // ---- Pass 2: thread owns col tx, output rows 4*ty .. 4*ty+3 (rolling
    // 3-row register window over the halo rows it needs) ----
    const int rbase = 4 * ty;
    float2 rA[3], rB[3], rC[3];
    #pragma unroll
    for (int c = 0; c < 3; ++c) {
        rA[c] = szk[rbase][tx + c];          // halo row rbase
        rB[c] = szk[rbase + 1][tx + c];      // halo row rbase+1
    }

    #pragma unroll
    for (int q = 0; q < 4; ++q) {
        const int rq = rbase + q;            // output row (tile coords); center = halo row rq+1
        #pragma unroll
        for (int c = 0; c < 3; ++c) rC[c] = szk[rq + 2][tx + c];

        // first-min over n=0..8; candidate z or 1e10 sentinel (mirrors
        // reference's where(gz>0, gz, INF) + argmin + val<INF check)
        float bz = 1e10f;
        int bli = rq + 1, blj = tx + 1;      // fallback: center
        #pragma unroll
        for (int t = 0; t < 3; ++t) {        // n = 0..2 -> row rq+2, lj = tx+2-t
            const float z = rC[2 - t].x;
            const int   k = __float_as_int(rC[2 - t].y);
            const float cand = (k == t && z > 0.f) ? z : 1e10f;
            if (cand < bz) { bz = cand; bli = rq + 2; blj = tx + 2 - t; }
        }
        #pragma unroll
        for (int t = 0; t < 3; ++t) {        // n = 3..5 -> row rq+1
            const float z = rB[2 - t].x;
            const int   k = __float_as_int(rB[2 - t].y);
            const float cand = (k == 3 + t && z > 0.f) ? z : 1e10f;
            if (cand < bz) { bz = cand; bli = rq + 1; blj = tx + 2 - t; }
        }
        #pragma unroll
        for (int t = 0; t < 3; ++t) {        // n = 6..8 -> row rq
            const float z = rA[2 - t].x;
            const int   k = __float_as_int(rA[2 - t].y);
            const float cand = (k == 6 + t && z > 0.f) ? z : 1e10f;
            if (cand < bz) { bz = cand; bli = rq; blj = tx + 2 - t; }
        }
        const bool found = bz < 1e10f;

        const float2 vxy = sxy[bli][blj];    // winner or center
        const float  vrm = srm[bli][blj];

        float ox, oy, oz, orm;
        if (found) {
            ox = vxy.x; oy = vxy.y; oz = bz; orm = vrm;
        } else {
            const int   kc = __float_as_int(rB[1].y);  // center code
            const float zc = rB[1].x;                  // center z
            const bool  k4 = (kc == 4);                // w_det(1,1) == 1
            const bool  validp = (vrm > 0.5f) && (zc > 0.f);
            ox = k4 ? vxy.x : 0.f;
            oy = k4 ? vxy.y : 0.f;
            oz = k4 ? zc    : 0.f;
            orm = (k4 || !validp) ? vrm : 0.f;         // w2(1,1)
        }

        const int h = h0 + rq, w = w0 + tx;
        const size_t obase = (size_t)b * 4 * HW + (size_t)h * W + w;
        __builtin_nontemporal_store(ox,  &out[obase]);
        __builtin_nontemporal_store(oy,  &out[obase + HW]);
        __builtin_nontemporal_store(oz,  &out[obase + 2 * HW]);
        __builtin_nontemporal_store(orm, &out[obase + 3 * HW]);

        #pragma unroll
        for (int c = 0; c < 3; ++c) { rA[c] = rB[c]; rB[c] = rC[c]; }
    }
}

extern "C" void kernel_launch(void* const* d_in, const int* in_sizes, int n_in,
                              void* d_out, int out_size, void* d_ws, size_t ws_size,
                              hipStream_t stream) {
    const float* x   = (const float*)d_in[0];
    const float* cam = (const float*)d_in[1];
    float* out = (float*)d_out;
    const int H = 512, W = 640;
    const int B = in_sizes[0] / (4 * H * W);
    dim3 block(32, 8);
    dim3 grid((W + BT - 1) / BT, (H + BT - 1) / BT, B);  // 20 x 16 x B, exact
    hipLaunchKernelGGL(smap_fused, grid, block, 0, stream, x, cam, out, B, H, W);
}